// Round 3
// baseline (1054.047 us; speedup 1.0000x reference)
//
#include <hip/hip_runtime.h>
#include <cstdint>

// ---------------------------------------------------------------------------
// 2-layer GCN with ZERO scattered global atomics.
//
// Nodes are split into 64-node buckets (bucket = col >> 6).
//  K1 hist:    per-chunk LDS histogram -> part[C][NB]        (non-atomic)
//  K2 colscan: per-bucket scan over chunks -> base[C][NB], tot[NB]
//  scan1/2/3:  exclusive scan tot -> start[NB+1]
//  K4 place:   rw[pos] = {row | col_local<<20, ew}           (normal stores)
//  K5 deg:     per-bucket LDS sum of ew -> dis = rsqrt(deg+1)
//  K6 xw1:     xs1 = (x @ W1^T) * dis                        [N,32]
//  K7 agg1:    U[64][32] in LDS += w * xs1[r]; h = relu(dis*(U+xs1)+b1)
//              then xs2 = (h @ W2^T) * dis  (h never leaves LDS)
//  K9 agg2:    U[64][16] in LDS += w * xs2[r]; out = dis*(U+xs2)+b2
// ---------------------------------------------------------------------------

#define BS 64           // nodes per bucket
#define CHUNKS 512      // edge chunks for hist/place

__global__ void hist_kernel(const int* __restrict__ col, int* __restrict__ part,
                            int E, int nbuck, int per) {
    extern __shared__ int sh[];
    for (int t = threadIdx.x; t < nbuck; t += blockDim.x) sh[t] = 0;
    __syncthreads();
    int lo = blockIdx.x * per, hi = min(E, lo + per);
    for (int e = lo + threadIdx.x; e < hi; e += blockDim.x)
        atomicAdd(&sh[col[e] >> 6], 1);
    __syncthreads();
    for (int t = threadIdx.x; t < nbuck; t += blockDim.x)
        part[(size_t)blockIdx.x * nbuck + t] = sh[t];
}

// per-bucket exclusive scan over the chunk axis (one wave per bucket)
__global__ void colscan_kernel(const int* __restrict__ part, int* __restrict__ base,
                               int* __restrict__ tot, int nbuck) {
    int b = blockIdx.x;
    if (b >= nbuck) return;
    int lane = threadIdx.x;  // 64
    int off = 0;
    for (int g = 0; g < CHUNKS; g += 64) {
        int c = g + lane;
        int v = part[(size_t)c * nbuck + b];
        int s = v;
        #pragma unroll
        for (int d = 1; d < 64; d <<= 1) {
            int t = __shfl_up(s, d);
            if (lane >= d) s += t;
        }
        base[(size_t)c * nbuck + b] = off + (s - v);
        off += __shfl(s, 63);
    }
    if (lane == 0) tot[b] = off;
}

// exclusive scan of tot -> start (3 kernels)
__global__ void scan1_kernel(const int* __restrict__ cnt, int* __restrict__ excl,
                             int* __restrict__ bsum, int n) {
    __shared__ int s[256];
    int tid = threadIdx.x;
    int i = blockIdx.x * 256 + tid;
    int v = (i < n) ? cnt[i] : 0;
    s[tid] = v;
    __syncthreads();
    for (int off = 1; off < 256; off <<= 1) {
        int t = (tid >= off) ? s[tid - off] : 0;
        __syncthreads();
        s[tid] += t;
        __syncthreads();
    }
    if (i < n) excl[i] = s[tid] - v;
    if (tid == 255) bsum[blockIdx.x] = s[255];
}

__global__ void scan2_kernel(int* __restrict__ bsum, int nb) {
    __shared__ int s[512];
    int tid = threadIdx.x;
    int v = (tid < nb) ? bsum[tid] : 0;
    s[tid] = v;
    __syncthreads();
    for (int off = 1; off < 512; off <<= 1) {
        int t = (tid >= off) ? s[tid - off] : 0;
        __syncthreads();
        s[tid] += t;
        __syncthreads();
    }
    if (tid < nb) bsum[tid] = s[tid] - v;
}

__global__ void scan3_kernel(int* __restrict__ excl, const int* __restrict__ bsum,
                             int n, int E) {
    int i = blockIdx.x * 256 + threadIdx.x;
    if (i < n) excl[i] += bsum[i >> 8];
    else if (i == n) excl[n] = E;
}

__global__ void place_kernel(const int* __restrict__ row, const int* __restrict__ col,
                             const float* __restrict__ ew,
                             const int* __restrict__ start, const int* __restrict__ base,
                             int2* __restrict__ rw, int E, int nbuck, int per) {
    extern __shared__ int sh[];
    int* lbase = sh;          // nbuck
    int* cnt2  = sh + nbuck;  // nbuck
    int c = blockIdx.x;
    for (int t = threadIdx.x; t < nbuck; t += blockDim.x) {
        lbase[t] = start[t] + base[(size_t)c * nbuck + t];
        cnt2[t] = 0;
    }
    __syncthreads();
    int lo = c * per, hi = min(E, lo + per);
    for (int e = lo + threadIdx.x; e < hi; e += blockDim.x) {
        int cc = col[e];
        int b = cc >> 6;
        int p = lbase[b] + atomicAdd(&cnt2[b], 1);
        int2 v;
        v.x = row[e] | ((cc & 63) << 20);   // row < 2^20 assumed (N = 100K)
        v.y = __float_as_int(ew[e]);
        rw[p] = v;
    }
}

__global__ void deg_kernel(const int2* __restrict__ rw, const int* __restrict__ start,
                           float* __restrict__ dis, int N) {
    __shared__ float sdeg[BS];
    if (threadIdx.x < BS) sdeg[threadIdx.x] = 0.f;
    __syncthreads();
    int b = blockIdx.x;
    int s0 = start[b], s1 = start[b + 1];
    for (int e = s0 + threadIdx.x; e < s1; e += blockDim.x) {
        int2 v = rw[e];
        atomicAdd(&sdeg[v.x >> 20], __int_as_float(v.y));
    }
    __syncthreads();
    if (threadIdx.x < BS) {
        int node = b * BS + threadIdx.x;
        if (node < N) dis[node] = rsqrtf(sdeg[threadIdx.x] + 1.0f);
    }
}

// xs1 = (x @ W1^T) * dis   (W1: [32,16] row-major)
__global__ void xw1_kernel(const float* __restrict__ x, const float* __restrict__ W1,
                           const float* __restrict__ dis, float* __restrict__ xs1, int N) {
    __shared__ float sW[512];
    for (int t = threadIdx.x; t < 512; t += blockDim.x) sW[t] = W1[t];
    __syncthreads();
    int i = blockIdx.x * blockDim.x + threadIdx.x;
    if (i >= N) return;
    float d = dis[i];
    float xr[16];
#pragma unroll
    for (int k = 0; k < 4; ++k) {
        float4 v = ((const float4*)(x + (size_t)i * 16))[k];
        xr[4*k+0] = v.x; xr[4*k+1] = v.y; xr[4*k+2] = v.z; xr[4*k+3] = v.w;
    }
    float* outp = xs1 + (size_t)i * 32;
#pragma unroll
    for (int o = 0; o < 32; ++o) {
        float acc = 0.f;
#pragma unroll
        for (int k = 0; k < 16; ++k) acc += xr[k] * sW[o*16 + k];
        outp[o] = acc * d;
    }
}

// agg1 + relu + (h @ W2^T)*dis fused. One block per bucket.
__global__ void agg1_kernel(const int2* __restrict__ rw, const int* __restrict__ start,
                            const float* __restrict__ xs1, const float* __restrict__ dis,
                            const float* __restrict__ b1, const float* __restrict__ W2,
                            float* __restrict__ xs2, int N) {
    __shared__ float U[BS * 33];     // padded: bank-conflict-free dot phase
    __shared__ float sW2[16 * 33];
    __shared__ float sb1[32];
    int tid = threadIdx.x;
    for (int t = tid; t < BS * 33; t += 256) U[t] = 0.f;
    for (int t = tid; t < 512; t += 256) sW2[(t >> 5) * 33 + (t & 31)] = W2[t];
    if (tid < 32) sb1[tid] = b1[tid];
    __syncthreads();

    int b = blockIdx.x;
    int s0 = start[b], s1 = start[b + 1];
    int f = tid & 31, slot = tid >> 5;   // 8 edge slots x 32 features
    for (int e = s0 + slot; e < s1; e += 8) {
        int2 v = rw[e];
        int r = v.x & 0xFFFFF, cl = v.x >> 20;
        atomicAdd(&U[cl * 33 + f], __int_as_float(v.y) * xs1[(size_t)r * 32 + f]);
    }
    __syncthreads();

    // h = relu(dis*(U + xs1_self) + b1), stored back into U
    for (int idx = tid; idx < BS * 32; idx += 256) {
        int cl = idx >> 5, ff = idx & 31;
        int node = b * BS + cl;
        if (node < N) {
            float d = dis[node];
            U[cl * 33 + ff] = fmaxf(d * (U[cl * 33 + ff] + xs1[(size_t)node * 32 + ff]) + sb1[ff], 0.f);
        }
    }
    __syncthreads();

    // xs2 = (h @ W2^T) * dis
    for (int idx = tid; idx < BS * 16; idx += 256) {
        int cl = idx >> 4, o = idx & 15;
        int node = b * BS + cl;
        if (node < N) {
            float acc = 0.f;
#pragma unroll
            for (int k = 0; k < 32; ++k) acc += U[cl * 33 + k] * sW2[o * 33 + k];
            xs2[(size_t)node * 16 + o] = acc * dis[node];
        }
    }
}

// agg2 + final epilogue. One block per bucket.
__global__ void agg2_kernel(const int2* __restrict__ rw, const int* __restrict__ start,
                            const float* __restrict__ xs2, const float* __restrict__ dis,
                            const float* __restrict__ b2, float* __restrict__ out, int N) {
    __shared__ float U[BS * 17];
    int tid = threadIdx.x;
    for (int t = tid; t < BS * 17; t += 256) U[t] = 0.f;
    __syncthreads();

    int b = blockIdx.x;
    int s0 = start[b], s1 = start[b + 1];
    int f = tid & 15, slot = tid >> 4;   // 16 edge slots x 16 features
    for (int e = s0 + slot; e < s1; e += 16) {
        int2 v = rw[e];
        int r = v.x & 0xFFFFF, cl = v.x >> 20;
        atomicAdd(&U[cl * 17 + f], __int_as_float(v.y) * xs2[(size_t)r * 16 + f]);
    }
    __syncthreads();

    for (int idx = tid; idx < BS * 16; idx += 256) {
        int cl = idx >> 4, ff = idx & 15;
        int node = b * BS + cl;
        if (node < N)
            out[(size_t)node * 16 + ff] =
                dis[node] * (U[cl * 17 + ff] + xs2[(size_t)node * 16 + ff]) + b2[ff];
    }
}

extern "C" void kernel_launch(void* const* d_in, const int* in_sizes, int n_in,
                              void* d_out, int out_size, void* d_ws, size_t ws_size,
                              hipStream_t stream) {
    const float* x  = (const float*)d_in[0];
    const int*   ei = (const int*)d_in[1];   // [2, E] int32
    const float* ew = (const float*)d_in[2];
    const float* W1 = (const float*)d_in[3];
    const float* b1 = (const float*)d_in[4];
    const float* W2 = (const float*)d_in[5];
    const float* b2 = (const float*)d_in[6];
    float* out = (float*)d_out;

    const int N = in_sizes[0] / 16;
    const int E = in_sizes[2];
    const int* row = ei;
    const int* col = ei + E;

    const int nbuck = (N + BS - 1) / BS;          // 1563
    const int per   = (E + CHUNKS - 1) / CHUNKS;  // edges per chunk
    const int nb    = (nbuck + 255) / 256;        // scan blocks (7)

    // workspace layout (4-byte units); rw first for 8B alignment
    float* ws    = (float*)d_ws;
    int2*  rw    = (int2*)ws;                              // 2E units
    float* xs1   = ws + (size_t)2 * E;                     // 32N
    float* xs2   = xs1 + (size_t)N * 32;                   // 16N
    float* dis   = xs2 + (size_t)N * 16;                   // N
    int*   part  = (int*)(dis + N);                        // CHUNKS*nbuck
    int*   base  = part + (size_t)CHUNKS * nbuck;          // CHUNKS*nbuck
    int*   tot   = base + (size_t)CHUNKS * nbuck;          // nbuck
    int*   start = tot + nbuck;                            // nbuck+1
    int*   bsum  = start + nbuck + 1;                      // <=512

    hist_kernel<<<CHUNKS, 256, nbuck * 4, stream>>>(col, part, E, nbuck, per);
    colscan_kernel<<<nbuck, 64, 0, stream>>>(part, base, tot, nbuck);
    scan1_kernel<<<nb, 256, 0, stream>>>(tot, start, bsum, nbuck);
    scan2_kernel<<<1, 512, 0, stream>>>(bsum, nb);
    scan3_kernel<<<(nbuck + 256) / 256 + 1, 256, 0, stream>>>(start, bsum, nbuck, E);
    place_kernel<<<CHUNKS, 256, 2 * nbuck * 4, stream>>>(row, col, ew, start, base, rw, E, nbuck, per);

    deg_kernel<<<nbuck, 256, 0, stream>>>(rw, start, dis, N);
    xw1_kernel<<<(N + 255) / 256, 256, 0, stream>>>(x, W1, dis, xs1, N);
    agg1_kernel<<<nbuck, 256, 0, stream>>>(rw, start, xs1, dis, b1, W2, xs2, N);
    agg2_kernel<<<nbuck, 256, 0, stream>>>(rw, start, xs2, dis, b2, out, N);
}

// Round 4
// 290.681 us; speedup vs baseline: 3.6261x; 3.6261x over previous
//
#include <hip/hip_runtime.h>
#include <cstdint>

// ---------------------------------------------------------------------------
// 2-layer GCN, zero scattered global atomics, per-node CSR gather.
//
//  K1 hist:     per-chunk LDS histogram of bucket=col>>6 -> part[C][NB]
//  K2 colscan:  per-bucket scan over chunks -> base[C][NB], tot[NB]
//  scan1/2/3:   exclusive scan tot -> start[NB+1]
//  K4 place:    rw[pos] = {row | cl<<20, ew}  (bucket-sorted, normal stores)
//  K5 nodesort: per-bucket LDS count/scan -> ptr[node], dis=rsqrt(deg+1),
//               rw2 = node-sorted edge list {row, ew}
//  K6 xw1:      xs1 = (x @ W1^T) * dis                         [N,32]
//  K7 gather1:  wave/node: h = relu(dis*(sum w*xs1[r] + xs1_self)+b1)
//               fused: xs2 = (h @ W2^T) * dis  (h stays in LDS) [N,16]
//  K8 gather2:  wave/node: out = dis*(sum w*xs2[r] + xs2_self)+b2
// ---------------------------------------------------------------------------

#define BS 64
#define CHUNKS 512

__global__ void hist_kernel(const int* __restrict__ col, int* __restrict__ part,
                            int E, int nbuck, int per) {
    extern __shared__ int sh[];
    for (int t = threadIdx.x; t < nbuck; t += blockDim.x) sh[t] = 0;
    __syncthreads();
    int lo = blockIdx.x * per, hi = min(E, lo + per);
    for (int e = lo + threadIdx.x; e < hi; e += blockDim.x)
        atomicAdd(&sh[col[e] >> 6], 1);
    __syncthreads();
    for (int t = threadIdx.x; t < nbuck; t += blockDim.x)
        part[(size_t)blockIdx.x * nbuck + t] = sh[t];
}

__global__ void colscan_kernel(const int* __restrict__ part, int* __restrict__ base,
                               int* __restrict__ tot, int nbuck) {
    int b = blockIdx.x;
    if (b >= nbuck) return;
    int lane = threadIdx.x;  // 64
    int off = 0;
    for (int g = 0; g < CHUNKS; g += 64) {
        int c = g + lane;
        int v = part[(size_t)c * nbuck + b];
        int s = v;
        #pragma unroll
        for (int d = 1; d < 64; d <<= 1) {
            int t = __shfl_up(s, d);
            if (lane >= d) s += t;
        }
        base[(size_t)c * nbuck + b] = off + (s - v);
        off += __shfl(s, 63);
    }
    if (lane == 0) tot[b] = off;
}

__global__ void scan1_kernel(const int* __restrict__ cnt, int* __restrict__ excl,
                             int* __restrict__ bsum, int n) {
    __shared__ int s[256];
    int tid = threadIdx.x;
    int i = blockIdx.x * 256 + tid;
    int v = (i < n) ? cnt[i] : 0;
    s[tid] = v;
    __syncthreads();
    for (int off = 1; off < 256; off <<= 1) {
        int t = (tid >= off) ? s[tid - off] : 0;
        __syncthreads();
        s[tid] += t;
        __syncthreads();
    }
    if (i < n) excl[i] = s[tid] - v;
    if (tid == 255) bsum[blockIdx.x] = s[255];
}

__global__ void scan2_kernel(int* __restrict__ bsum, int nb) {
    __shared__ int s[512];
    int tid = threadIdx.x;
    int v = (tid < nb) ? bsum[tid] : 0;
    s[tid] = v;
    __syncthreads();
    for (int off = 1; off < 512; off <<= 1) {
        int t = (tid >= off) ? s[tid - off] : 0;
        __syncthreads();
        s[tid] += t;
        __syncthreads();
    }
    if (tid < nb) bsum[tid] = s[tid] - v;
}

__global__ void scan3_kernel(int* __restrict__ excl, const int* __restrict__ bsum,
                             int n, int E) {
    int i = blockIdx.x * 256 + threadIdx.x;
    if (i < n) excl[i] += bsum[i >> 8];
    else if (i == n) excl[n] = E;
}

__global__ void place_kernel(const int* __restrict__ row, const int* __restrict__ col,
                             const float* __restrict__ ew,
                             const int* __restrict__ start, const int* __restrict__ base,
                             int2* __restrict__ rw, int E, int nbuck, int per) {
    extern __shared__ int sh[];
    int* lbase = sh;
    int* cnt2  = sh + nbuck;
    int c = blockIdx.x;
    for (int t = threadIdx.x; t < nbuck; t += blockDim.x) {
        lbase[t] = start[t] + base[(size_t)c * nbuck + t];
        cnt2[t] = 0;
    }
    __syncthreads();
    int lo = c * per, hi = min(E, lo + per);
    for (int e = lo + threadIdx.x; e < hi; e += blockDim.x) {
        int cc = col[e];
        int b = cc >> 6;
        int p = lbase[b] + atomicAdd(&cnt2[b], 1);
        int2 v;
        v.x = row[e] | ((cc & 63) << 20);
        v.y = __float_as_int(ew[e]);
        rw[p] = v;
    }
}

// per-bucket: per-node counts -> ptr, dis; node-sorted rw2
__global__ void nodesort_kernel(const int2* __restrict__ rw, const int* __restrict__ start,
                                int2* __restrict__ rw2, int* __restrict__ ptr,
                                float* __restrict__ dis, int N, int E, int nbuck) {
    __shared__ int cnt[BS];
    __shared__ float fdeg[BS];
    __shared__ int fill[BS];
    int b = blockIdx.x, tid = threadIdx.x;
    if (tid < BS) { cnt[tid] = 0; fdeg[tid] = 0.f; }
    __syncthreads();
    int s0 = start[b], s1 = start[b + 1];
    for (int e = s0 + tid; e < s1; e += 256) {
        int2 v = rw[e];
        int cl = v.x >> 20;
        atomicAdd(&cnt[cl], 1);
        atomicAdd(&fdeg[cl], __int_as_float(v.y));
    }
    __syncthreads();
    if (tid < BS) {
        int c = cnt[tid];
        int s = c;
        #pragma unroll
        for (int d = 1; d < BS; d <<= 1) {
            int t = __shfl_up(s, d);
            if (tid >= d) s += t;
        }
        int excl = s - c;
        ptr[b * BS + tid] = s0 + excl;
        fill[tid] = excl;
        int node = b * BS + tid;
        if (node < N) dis[node] = rsqrtf(fdeg[tid] + 1.0f);
    }
    __syncthreads();
    for (int e = s0 + tid; e < s1; e += 256) {
        int2 v = rw[e];
        int cl = v.x >> 20;
        int p = s0 + atomicAdd(&fill[cl], 1);
        int2 o;
        o.x = v.x & 0xFFFFF;
        o.y = v.y;
        rw2[p] = o;
    }
    if (b == 0 && tid == 0) ptr[nbuck * BS] = E;
}

// xs1 = (x @ W1^T) * dis   (W1: [32,16] row-major)
__global__ void xw1_kernel(const float* __restrict__ x, const float* __restrict__ W1,
                           const float* __restrict__ dis, float* __restrict__ xs1, int N) {
    __shared__ float sW[512];
    for (int t = threadIdx.x; t < 512; t += blockDim.x) sW[t] = W1[t];
    __syncthreads();
    int i = blockIdx.x * blockDim.x + threadIdx.x;
    if (i >= N) return;
    float d = dis[i];
    float xr[16];
#pragma unroll
    for (int k = 0; k < 4; ++k) {
        float4 v = ((const float4*)(x + (size_t)i * 16))[k];
        xr[4*k+0] = v.x; xr[4*k+1] = v.y; xr[4*k+2] = v.z; xr[4*k+3] = v.w;
    }
    float* outp = xs1 + (size_t)i * 32;
#pragma unroll
    for (int o = 0; o < 32; ++o) {
        float acc = 0.f;
#pragma unroll
        for (int k = 0; k < 16; ++k) acc += xr[k] * sW[o*16 + k];
        outp[o] = acc * d;
    }
}

// wave per node; fused: aggregate layer 1 + relu + (h @ W2^T)*dis -> xs2
__global__ __launch_bounds__(256) void gather1_kernel(
        const int* __restrict__ ptr, const int2* __restrict__ rw2,
        const float* __restrict__ xs1, const float* __restrict__ dis,
        const float* __restrict__ b1, const float* __restrict__ W2,
        float* __restrict__ xs2, int N) {
    __shared__ float sW2[16 * 33];   // padded, conflict-free dot
    __shared__ float hbuf[4 * 32];
    for (int t = threadIdx.x; t < 512; t += 256) sW2[(t >> 5) * 33 + (t & 31)] = W2[t];

    int node = (blockIdx.x * 256 + threadIdx.x) >> 6;
    int wloc = threadIdx.x >> 6;
    int lane = threadIdx.x & 63;
    int f = lane & 31, slot = lane >> 5;
    bool valid = node < N;

    int s0 = 0, s1 = 0;
    if (valid) { s0 = ptr[node]; s1 = ptr[node + 1]; }

    float acc0 = 0.f, acc1 = 0.f;
    int e = s0 + slot;
    for (; e + 2 < s1; e += 4) {
        int2 v0 = rw2[e];
        int2 v1 = rw2[e + 2];
        acc0 += __int_as_float(v0.y) * xs1[(size_t)v0.x * 32 + f];
        acc1 += __int_as_float(v1.y) * xs1[(size_t)v1.x * 32 + f];
    }
    if (e < s1) {
        int2 v = rw2[e];
        acc0 += __int_as_float(v.y) * xs1[(size_t)v.x * 32 + f];
    }
    float acc = acc0 + acc1;
    acc += __shfl_xor(acc, 32);

    float h = 0.f;
    float d = valid ? dis[node] : 0.f;
    if (valid) h = fmaxf(d * (acc + xs1[(size_t)node * 32 + f]) + b1[f], 0.f);
    if (slot == 0) hbuf[wloc * 32 + f] = h;
    __syncthreads();

    if (valid && lane < 16) {
        float a = 0.f;
#pragma unroll
        for (int k = 0; k < 32; ++k) a += hbuf[wloc * 32 + k] * sW2[lane * 33 + k];
        xs2[(size_t)node * 16 + lane] = a * d;
    }
}

// wave per node; aggregate layer 2 + final epilogue -> out
__global__ __launch_bounds__(256) void gather2_kernel(
        const int* __restrict__ ptr, const int2* __restrict__ rw2,
        const float* __restrict__ xs2, const float* __restrict__ dis,
        const float* __restrict__ b2, float* __restrict__ out, int N) {
    int node = (blockIdx.x * 256 + threadIdx.x) >> 6;
    int lane = threadIdx.x & 63;
    int f = lane & 15, slot = lane >> 4;
    if (node >= N) return;
    int s0 = ptr[node], s1 = ptr[node + 1];

    float acc0 = 0.f, acc1 = 0.f;
    int e = s0 + slot;
    for (; e + 4 < s1; e += 8) {
        int2 v0 = rw2[e];
        int2 v1 = rw2[e + 4];
        acc0 += __int_as_float(v0.y) * xs2[(size_t)v0.x * 16 + f];
        acc1 += __int_as_float(v1.y) * xs2[(size_t)v1.x * 16 + f];
    }
    if (e < s1) {
        int2 v = rw2[e];
        acc0 += __int_as_float(v.y) * xs2[(size_t)v.x * 16 + f];
    }
    float acc = acc0 + acc1;
    acc += __shfl_xor(acc, 16);
    acc += __shfl_xor(acc, 32);
    if (slot == 0) {
        float d = dis[node];
        out[(size_t)node * 16 + f] = d * (acc + xs2[(size_t)node * 16 + f]) + b2[f];
    }
}

extern "C" void kernel_launch(void* const* d_in, const int* in_sizes, int n_in,
                              void* d_out, int out_size, void* d_ws, size_t ws_size,
                              hipStream_t stream) {
    const float* x  = (const float*)d_in[0];
    const int*   ei = (const int*)d_in[1];   // [2, E] int32
    const float* ew = (const float*)d_in[2];
    const float* W1 = (const float*)d_in[3];
    const float* b1 = (const float*)d_in[4];
    const float* W2 = (const float*)d_in[5];
    const float* b2 = (const float*)d_in[6];
    float* out = (float*)d_out;

    const int N = in_sizes[0] / 16;
    const int E = in_sizes[2];
    const int* row = ei;
    const int* col = ei + E;

    const int nbuck = (N + BS - 1) / BS;          // 1563
    const int per   = (E + CHUNKS - 1) / CHUNKS;
    const int nb    = (nbuck + 255) / 256;        // 7

    // workspace layout (4B units)
    //  [0, 2E)        : rw2 (node-sorted, int2)
    //  [2E, 4E)       : rw (bucket-sorted, int2) -- DEAD after nodesort;
    //                   then reused: xs1 [32N] at 2E, xs2 [16N] at 2E+32N
    //                   (32N + 16N = 4.8M <= 2E = 6.4M)
    //  [4E, ...)      : dis[N], ptr[BS*nbuck+1], part, base, tot, start, bsum
    float* ws    = (float*)d_ws;
    int2*  rw2   = (int2*)ws;
    int2*  rw    = (int2*)(ws + (size_t)2 * E);
    float* xs1   = ws + (size_t)2 * E;
    float* xs2   = xs1 + (size_t)N * 32;
    float* dis   = ws + (size_t)4 * E;
    int*   ptr   = (int*)(dis + N);
    int*   part  = ptr + (size_t)BS * nbuck + 1;
    int*   base  = part + (size_t)CHUNKS * nbuck;
    int*   tot   = base + (size_t)CHUNKS * nbuck;
    int*   start = tot + nbuck;
    int*   bsum  = start + nbuck + 1;

    hist_kernel<<<CHUNKS, 256, nbuck * 4, stream>>>(col, part, E, nbuck, per);
    colscan_kernel<<<nbuck, 64, 0, stream>>>(part, base, tot, nbuck);
    scan1_kernel<<<nb, 256, 0, stream>>>(tot, start, bsum, nbuck);
    scan2_kernel<<<1, 512, 0, stream>>>(bsum, nb);
    scan3_kernel<<<(nbuck + 256) / 256 + 1, 256, 0, stream>>>(start, bsum, nbuck, E);
    place_kernel<<<CHUNKS, 256, 2 * nbuck * 4, stream>>>(row, col, ew, start, base, rw, E, nbuck, per);
    nodesort_kernel<<<nbuck, 256, 0, stream>>>(rw, start, rw2, ptr, dis, N, E, nbuck);

    xw1_kernel<<<(N + 255) / 256, 256, 0, stream>>>(x, W1, dis, xs1, N);
    gather1_kernel<<<(N + 3) / 4, 256, 0, stream>>>(ptr, rw2, xs1, dis, b1, W2, xs2, N);
    gather2_kernel<<<(N + 3) / 4, 256, 0, stream>>>(ptr, rw2, xs2, dis, b2, out, N);
}

// Round 5
// 223.000 us; speedup vs baseline: 4.7267x; 1.3035x over previous
//
#include <hip/hip_runtime.h>
#include <cstdint>

// ---------------------------------------------------------------------------
// 2-layer GCN, zero scattered global atomics, per-node CSR gather with
// float4-wide gathers (8 edges per wave-iteration in layer 1, 16 in layer 2).
//
//  K1 hist:     per-chunk LDS histogram of bucket=col>>6 -> part[C][NB]
//  K2 colscan:  per-bucket scan over chunks -> base[C][NB], tot[NB]
//  scan1/2/3:   exclusive scan tot -> start[NB+1]
//  K4 place:    rw[pos] = {row | cl<<20, ew}  (bucket-sorted, normal stores)
//  K5 nodesort: per-bucket LDS count/scan -> ptr[node], dis=rsqrt(deg+1),
//               rw2 = node-sorted edge list {row, ew}
//  K6 xw1:      xs1 = (x @ W1^T) * dis                         [N,32]
//  K7 gather1:  wave/node, float4 lanes: h = relu(dis*(agg+self)+b1);
//               fused xs2 = (h @ W2^T) * dis  (h stays in LDS)  [N,16]
//  K8 gather2:  wave/node, float4 lanes: out = dis*(agg+self)+b2
// ---------------------------------------------------------------------------

#define BS 64
#define CHUNKS 512

__global__ void hist_kernel(const int* __restrict__ col, int* __restrict__ part,
                            int E, int nbuck, int per) {
    extern __shared__ int sh[];
    for (int t = threadIdx.x; t < nbuck; t += blockDim.x) sh[t] = 0;
    __syncthreads();
    int lo = blockIdx.x * per, hi = min(E, lo + per);
    for (int e = lo + threadIdx.x; e < hi; e += blockDim.x)
        atomicAdd(&sh[col[e] >> 6], 1);
    __syncthreads();
    for (int t = threadIdx.x; t < nbuck; t += blockDim.x)
        part[(size_t)blockIdx.x * nbuck + t] = sh[t];
}

__global__ void colscan_kernel(const int* __restrict__ part, int* __restrict__ base,
                               int* __restrict__ tot, int nbuck) {
    int b = blockIdx.x;
    if (b >= nbuck) return;
    int lane = threadIdx.x;  // 64
    int off = 0;
    for (int g = 0; g < CHUNKS; g += 64) {
        int c = g + lane;
        int v = part[(size_t)c * nbuck + b];
        int s = v;
        #pragma unroll
        for (int d = 1; d < 64; d <<= 1) {
            int t = __shfl_up(s, d);
            if (lane >= d) s += t;
        }
        base[(size_t)c * nbuck + b] = off + (s - v);
        off += __shfl(s, 63);
    }
    if (lane == 0) tot[b] = off;
}

__global__ void scan1_kernel(const int* __restrict__ cnt, int* __restrict__ excl,
                             int* __restrict__ bsum, int n) {
    __shared__ int s[256];
    int tid = threadIdx.x;
    int i = blockIdx.x * 256 + tid;
    int v = (i < n) ? cnt[i] : 0;
    s[tid] = v;
    __syncthreads();
    for (int off = 1; off < 256; off <<= 1) {
        int t = (tid >= off) ? s[tid - off] : 0;
        __syncthreads();
        s[tid] += t;
        __syncthreads();
    }
    if (i < n) excl[i] = s[tid] - v;
    if (tid == 255) bsum[blockIdx.x] = s[255];
}

__global__ void scan2_kernel(int* __restrict__ bsum, int nb) {
    __shared__ int s[512];
    int tid = threadIdx.x;
    int v = (tid < nb) ? bsum[tid] : 0;
    s[tid] = v;
    __syncthreads();
    for (int off = 1; off < 512; off <<= 1) {
        int t = (tid >= off) ? s[tid - off] : 0;
        __syncthreads();
        s[tid] += t;
        __syncthreads();
    }
    if (tid < nb) bsum[tid] = s[tid] - v;
}

__global__ void scan3_kernel(int* __restrict__ excl, const int* __restrict__ bsum,
                             int n, int E) {
    int i = blockIdx.x * 256 + threadIdx.x;
    if (i < n) excl[i] += bsum[i >> 8];
    else if (i == n) excl[n] = E;
}

__global__ void place_kernel(const int* __restrict__ row, const int* __restrict__ col,
                             const float* __restrict__ ew,
                             const int* __restrict__ start, const int* __restrict__ base,
                             int2* __restrict__ rw, int E, int nbuck, int per) {
    extern __shared__ int sh[];
    int* lbase = sh;
    int* cnt2  = sh + nbuck;
    int c = blockIdx.x;
    for (int t = threadIdx.x; t < nbuck; t += blockDim.x) {
        lbase[t] = start[t] + base[(size_t)c * nbuck + t];
        cnt2[t] = 0;
    }
    __syncthreads();
    int lo = c * per, hi = min(E, lo + per);
    for (int e = lo + threadIdx.x; e < hi; e += blockDim.x) {
        int cc = col[e];
        int b = cc >> 6;
        int p = lbase[b] + atomicAdd(&cnt2[b], 1);
        int2 v;
        v.x = row[e] | ((cc & 63) << 20);
        v.y = __float_as_int(ew[e]);
        rw[p] = v;
    }
}

// per-bucket: per-node counts -> ptr, dis; node-sorted rw2 (row bits stripped)
__global__ void nodesort_kernel(const int2* __restrict__ rw, const int* __restrict__ start,
                                int2* __restrict__ rw2, int* __restrict__ ptr,
                                float* __restrict__ dis, int N, int E, int nbuck) {
    __shared__ int cnt[BS];
    __shared__ float fdeg[BS];
    __shared__ int fill[BS];
    int b = blockIdx.x, tid = threadIdx.x;
    if (tid < BS) { cnt[tid] = 0; fdeg[tid] = 0.f; }
    __syncthreads();
    int s0 = start[b], s1 = start[b + 1];
    for (int e = s0 + tid; e < s1; e += 256) {
        int2 v = rw[e];
        int cl = v.x >> 20;
        atomicAdd(&cnt[cl], 1);
        atomicAdd(&fdeg[cl], __int_as_float(v.y));
    }
    __syncthreads();
    if (tid < BS) {
        int c = cnt[tid];
        int s = c;
        #pragma unroll
        for (int d = 1; d < BS; d <<= 1) {
            int t = __shfl_up(s, d);
            if (tid >= d) s += t;
        }
        int excl = s - c;
        ptr[b * BS + tid] = s0 + excl;
        fill[tid] = excl;
        int node = b * BS + tid;
        if (node < N) dis[node] = rsqrtf(fdeg[tid] + 1.0f);
    }
    __syncthreads();
    for (int e = s0 + tid; e < s1; e += 256) {
        int2 v = rw[e];
        int cl = v.x >> 20;
        int p = s0 + atomicAdd(&fill[cl], 1);
        int2 o;
        o.x = v.x & 0xFFFFF;
        o.y = v.y;
        rw2[p] = o;
    }
    if (b == 0 && tid == 0) ptr[nbuck * BS] = E;
}

// xs1 = (x @ W1^T) * dis   (W1: [32,16] row-major)
__global__ void xw1_kernel(const float* __restrict__ x, const float* __restrict__ W1,
                           const float* __restrict__ dis, float* __restrict__ xs1, int N) {
    __shared__ float sW[512];
    for (int t = threadIdx.x; t < 512; t += blockDim.x) sW[t] = W1[t];
    __syncthreads();
    int i = blockIdx.x * blockDim.x + threadIdx.x;
    if (i >= N) return;
    float d = dis[i];
    float xr[16];
#pragma unroll
    for (int k = 0; k < 4; ++k) {
        float4 v = ((const float4*)(x + (size_t)i * 16))[k];
        xr[4*k+0] = v.x; xr[4*k+1] = v.y; xr[4*k+2] = v.z; xr[4*k+3] = v.w;
    }
    float* outp = xs1 + (size_t)i * 32;
#pragma unroll
    for (int o = 0; o < 32; ++o) {
        float acc = 0.f;
#pragma unroll
        for (int k = 0; k < 16; ++k) acc += xr[k] * sW[o*16 + k];
        outp[o] = acc * d;
    }
}

// wave per node; lane = slot(8) x quad(8); 8 edges per iteration, float4 loads.
// fused: h = relu(dis*(agg+self)+b1); xs2 = (h @ W2^T)*dis  (h via LDS)
__global__ __launch_bounds__(256) void gather1_kernel(
        const int* __restrict__ ptr, const int2* __restrict__ rw2,
        const float* __restrict__ xs1, const float* __restrict__ dis,
        const float* __restrict__ b1, const float* __restrict__ W2,
        float* __restrict__ xs2, int N) {
    __shared__ float sW2[16 * 33];   // padded, conflict-free dot
    __shared__ float hbuf[4 * 32];
    for (int t = threadIdx.x; t < 512; t += 256) sW2[(t >> 5) * 33 + (t & 31)] = W2[t];

    int node = (blockIdx.x * 256 + threadIdx.x) >> 6;
    int wloc = threadIdx.x >> 6;
    int lane = threadIdx.x & 63;
    int slot = lane >> 3;          // 8 edge slots
    int q    = lane & 7;           // 8 float4 quads = 32 features
    bool valid = node < N;

    int s0 = 0, s1 = 0;
    if (valid) { s0 = ptr[node]; s1 = ptr[node + 1]; }

    float4 a0 = {0.f, 0.f, 0.f, 0.f}, a1 = {0.f, 0.f, 0.f, 0.f};
    int e = s0 + slot;
    for (; e + 8 < s1; e += 16) {              // 2-way unroll, stride 8/slot
        int2 v0 = rw2[e];
        int2 v1 = rw2[e + 8];
        float4 x0 = *(const float4*)(xs1 + (size_t)v0.x * 32 + q * 4);
        float4 x1 = *(const float4*)(xs1 + (size_t)v1.x * 32 + q * 4);
        float w0 = __int_as_float(v0.y), w1 = __int_as_float(v1.y);
        a0.x += w0 * x0.x; a0.y += w0 * x0.y; a0.z += w0 * x0.z; a0.w += w0 * x0.w;
        a1.x += w1 * x1.x; a1.y += w1 * x1.y; a1.z += w1 * x1.z; a1.w += w1 * x1.w;
    }
    if (e < s1) {
        int2 v0 = rw2[e];
        float4 x0 = *(const float4*)(xs1 + (size_t)v0.x * 32 + q * 4);
        float w0 = __int_as_float(v0.y);
        a0.x += w0 * x0.x; a0.y += w0 * x0.y; a0.z += w0 * x0.z; a0.w += w0 * x0.w;
    }
    a0.x += a1.x; a0.y += a1.y; a0.z += a1.z; a0.w += a1.w;
#pragma unroll
    for (int m = 8; m <= 32; m <<= 1) {        // reduce across 8 slots
        a0.x += __shfl_xor(a0.x, m);
        a0.y += __shfl_xor(a0.y, m);
        a0.z += __shfl_xor(a0.z, m);
        a0.w += __shfl_xor(a0.w, m);
    }

    float d = valid ? dis[node] : 0.f;
    if (valid && slot == 0) {
        float4 self = *(const float4*)(xs1 + (size_t)node * 32 + q * 4);
        float4 bb   = *(const float4*)(b1 + q * 4);
        float4 h;
        h.x = fmaxf(d * (a0.x + self.x) + bb.x, 0.f);
        h.y = fmaxf(d * (a0.y + self.y) + bb.y, 0.f);
        h.z = fmaxf(d * (a0.z + self.z) + bb.z, 0.f);
        h.w = fmaxf(d * (a0.w + self.w) + bb.w, 0.f);
        *(float4*)(hbuf + wloc * 32 + q * 4) = h;
    }
    __syncthreads();

    if (valid && lane < 16) {
        float a = 0.f;
#pragma unroll
        for (int k = 0; k < 32; ++k) a += hbuf[wloc * 32 + k] * sW2[lane * 33 + k];
        xs2[(size_t)node * 16 + lane] = a * d;
    }
}

// wave per node; lane = slot(16) x quad(4); 16 edges per iteration.
__global__ __launch_bounds__(256) void gather2_kernel(
        const int* __restrict__ ptr, const int2* __restrict__ rw2,
        const float* __restrict__ xs2, const float* __restrict__ dis,
        const float* __restrict__ b2, float* __restrict__ out, int N) {
    int node = (blockIdx.x * 256 + threadIdx.x) >> 6;
    int lane = threadIdx.x & 63;
    int slot = lane >> 2;          // 16 edge slots
    int q    = lane & 3;           // 4 float4 quads = 16 features
    if (node >= N) return;
    int s0 = ptr[node], s1 = ptr[node + 1];

    float4 a0 = {0.f, 0.f, 0.f, 0.f}, a1 = {0.f, 0.f, 0.f, 0.f};
    int e = s0 + slot;
    for (; e + 16 < s1; e += 32) {             // 2-way unroll, stride 16/slot
        int2 v0 = rw2[e];
        int2 v1 = rw2[e + 16];
        float4 x0 = *(const float4*)(xs2 + (size_t)v0.x * 16 + q * 4);
        float4 x1 = *(const float4*)(xs2 + (size_t)v1.x * 16 + q * 4);
        float w0 = __int_as_float(v0.y), w1 = __int_as_float(v1.y);
        a0.x += w0 * x0.x; a0.y += w0 * x0.y; a0.z += w0 * x0.z; a0.w += w0 * x0.w;
        a1.x += w1 * x1.x; a1.y += w1 * x1.y; a1.z += w1 * x1.z; a1.w += w1 * x1.w;
    }
    if (e < s1) {
        int2 v0 = rw2[e];
        float4 x0 = *(const float4*)(xs2 + (size_t)v0.x * 16 + q * 4);
        float w0 = __int_as_float(v0.y);
        a0.x += w0 * x0.x; a0.y += w0 * x0.y; a0.z += w0 * x0.z; a0.w += w0 * x0.w;
    }
    a0.x += a1.x; a0.y += a1.y; a0.z += a1.z; a0.w += a1.w;
#pragma unroll
    for (int m = 4; m <= 32; m <<= 1) {        // reduce across 16 slots
        a0.x += __shfl_xor(a0.x, m);
        a0.y += __shfl_xor(a0.y, m);
        a0.z += __shfl_xor(a0.z, m);
        a0.w += __shfl_xor(a0.w, m);
    }

    if (slot == 0) {
        float d = dis[node];
        float4 self = *(const float4*)(xs2 + (size_t)node * 16 + q * 4);
        float4 bb   = *(const float4*)(b2 + q * 4);
        float4 o;
        o.x = d * (a0.x + self.x) + bb.x;
        o.y = d * (a0.y + self.y) + bb.y;
        o.z = d * (a0.z + self.z) + bb.z;
        o.w = d * (a0.w + self.w) + bb.w;
        *(float4*)(out + (size_t)node * 16 + q * 4) = o;
    }
}

extern "C" void kernel_launch(void* const* d_in, const int* in_sizes, int n_in,
                              void* d_out, int out_size, void* d_ws, size_t ws_size,
                              hipStream_t stream) {
    const float* x  = (const float*)d_in[0];
    const int*   ei = (const int*)d_in[1];   // [2, E] int32
    const float* ew = (const float*)d_in[2];
    const float* W1 = (const float*)d_in[3];
    const float* b1 = (const float*)d_in[4];
    const float* W2 = (const float*)d_in[5];
    const float* b2 = (const float*)d_in[6];
    float* out = (float*)d_out;

    const int N = in_sizes[0] / 16;
    const int E = in_sizes[2];
    const int* row = ei;
    const int* col = ei + E;

    const int nbuck = (N + BS - 1) / BS;          // 1563
    const int per   = (E + CHUNKS - 1) / CHUNKS;
    const int nb    = (nbuck + 255) / 256;        // 7

    // workspace layout (4B units)
    //  [0, 2E)   : rw2 (node-sorted int2)
    //  [2E, 4E)  : rw (bucket-sorted int2), DEAD after nodesort;
    //              reused: xs1 [32N] at 2E, xs2 [16N] at 2E+32N (48N <= 2E)
    //  [4E, ...) : dis[N], ptr[BS*nbuck+1], part, base, tot, start, bsum
    float* ws    = (float*)d_ws;
    int2*  rw2   = (int2*)ws;
    int2*  rw    = (int2*)(ws + (size_t)2 * E);
    float* xs1   = ws + (size_t)2 * E;
    float* xs2   = xs1 + (size_t)N * 32;
    float* dis   = ws + (size_t)4 * E;
    int*   ptr   = (int*)(dis + N);
    int*   part  = ptr + (size_t)BS * nbuck + 1;
    int*   base  = part + (size_t)CHUNKS * nbuck;
    int*   tot   = base + (size_t)CHUNKS * nbuck;
    int*   start = tot + nbuck;
    int*   bsum  = start + nbuck + 1;

    hist_kernel<<<CHUNKS, 256, nbuck * 4, stream>>>(col, part, E, nbuck, per);
    colscan_kernel<<<nbuck, 64, 0, stream>>>(part, base, tot, nbuck);
    scan1_kernel<<<nb, 256, 0, stream>>>(tot, start, bsum, nbuck);
    scan2_kernel<<<1, 512, 0, stream>>>(bsum, nb);
    scan3_kernel<<<(nbuck + 256) / 256 + 1, 256, 0, stream>>>(start, bsum, nbuck, E);
    place_kernel<<<CHUNKS, 256, 2 * nbuck * 4, stream>>>(row, col, ew, start, base, rw, E, nbuck, per);
    nodesort_kernel<<<nbuck, 256, 0, stream>>>(rw, start, rw2, ptr, dis, N, E, nbuck);

    xw1_kernel<<<(N + 255) / 256, 256, 0, stream>>>(x, W1, dis, xs1, N);
    gather1_kernel<<<(N + 3) / 4, 256, 0, stream>>>(ptr, rw2, xs1, dis, b1, W2, xs2, N);
    gather2_kernel<<<(N + 3) / 4, 256, 0, stream>>>(ptr, rw2, xs2, dis, b2, out, N);
}

// Round 6
// 216.953 us; speedup vs baseline: 4.8584x; 1.0279x over previous
//
#include <hip/hip_runtime.h>
#include <cstdint>

// ---------------------------------------------------------------------------
// 2-layer GCN, zero scattered global atomics, per-node CSR gather with
// float4-wide gathers. Build kernels run 1024-thread blocks for occupancy.
//
//  K1 hist:     per-chunk LDS histogram of bucket=col>>6 -> part[C][NB]
//  K2 colscan:  per-bucket scan over chunks -> base[C][NB], tot[NB]
//  scan1/2/3:   exclusive scan tot -> start[NB+1]
//  K4 place:    rw[pos] = {row | cl<<20, ew}  (bucket-sorted, normal stores)
//  K5 nodesort: per-bucket LDS count/scan -> ptr[node], dis=rsqrt(deg+1),
//               rw2 = node-sorted edge list {row, ew}
//  K6 xw1:      xs1 = (x @ W1^T) * dis                         [N,32]
//  K7 gather1:  wave/node, float4 lanes: h = relu(dis*(agg+self)+b1);
//               fused xs2 = (h @ W2^T) * dis  (h stays in LDS)  [N,16]
//  K8 gather2:  wave/node, float4 lanes: out = dis*(agg+self)+b2
// ---------------------------------------------------------------------------

#define BS 64
#define CHUNKS 512

__global__ __launch_bounds__(1024) void hist_kernel(
        const int* __restrict__ col, int* __restrict__ part,
        int E, int nbuck, int per) {
    extern __shared__ int sh[];
    for (int t = threadIdx.x; t < nbuck; t += blockDim.x) sh[t] = 0;
    __syncthreads();
    int lo = blockIdx.x * per, hi = min(E, lo + per);
    for (int e = lo + threadIdx.x; e < hi; e += blockDim.x)
        atomicAdd(&sh[col[e] >> 6], 1);
    __syncthreads();
    for (int t = threadIdx.x; t < nbuck; t += blockDim.x)
        part[(size_t)blockIdx.x * nbuck + t] = sh[t];
}

__global__ void colscan_kernel(const int* __restrict__ part, int* __restrict__ base,
                               int* __restrict__ tot, int nbuck) {
    int b = blockIdx.x;
    if (b >= nbuck) return;
    int lane = threadIdx.x;  // 64
    int off = 0;
    for (int g = 0; g < CHUNKS; g += 64) {
        int c = g + lane;
        int v = part[(size_t)c * nbuck + b];
        int s = v;
        #pragma unroll
        for (int d = 1; d < 64; d <<= 1) {
            int t = __shfl_up(s, d);
            if (lane >= d) s += t;
        }
        base[(size_t)c * nbuck + b] = off + (s - v);
        off += __shfl(s, 63);
    }
    if (lane == 0) tot[b] = off;
}

__global__ void scan1_kernel(const int* __restrict__ cnt, int* __restrict__ excl,
                             int* __restrict__ bsum, int n) {
    __shared__ int s[256];
    int tid = threadIdx.x;
    int i = blockIdx.x * 256 + tid;
    int v = (i < n) ? cnt[i] : 0;
    s[tid] = v;
    __syncthreads();
    for (int off = 1; off < 256; off <<= 1) {
        int t = (tid >= off) ? s[tid - off] : 0;
        __syncthreads();
        s[tid] += t;
        __syncthreads();
    }
    if (i < n) excl[i] = s[tid] - v;
    if (tid == 255) bsum[blockIdx.x] = s[255];
}

__global__ void scan2_kernel(int* __restrict__ bsum, int nb) {
    __shared__ int s[512];
    int tid = threadIdx.x;
    int v = (tid < nb) ? bsum[tid] : 0;
    s[tid] = v;
    __syncthreads();
    for (int off = 1; off < 512; off <<= 1) {
        int t = (tid >= off) ? s[tid - off] : 0;
        __syncthreads();
        s[tid] += t;
        __syncthreads();
    }
    if (tid < nb) bsum[tid] = s[tid] - v;
}

__global__ void scan3_kernel(int* __restrict__ excl, const int* __restrict__ bsum,
                             int n, int E) {
    int i = blockIdx.x * 256 + threadIdx.x;
    if (i < n) excl[i] += bsum[i >> 8];
    else if (i == n) excl[n] = E;
}

__global__ __launch_bounds__(1024) void place_kernel(
        const int* __restrict__ row, const int* __restrict__ col,
        const float* __restrict__ ew,
        const int* __restrict__ start, const int* __restrict__ base,
        int2* __restrict__ rw, int E, int nbuck, int per) {
    extern __shared__ int sh[];
    int* lbase = sh;
    int* cnt2  = sh + nbuck;
    int c = blockIdx.x;
    for (int t = threadIdx.x; t < nbuck; t += blockDim.x) {
        lbase[t] = start[t] + base[(size_t)c * nbuck + t];
        cnt2[t] = 0;
    }
    __syncthreads();
    int lo = c * per, hi = min(E, lo + per);
    for (int e = lo + threadIdx.x; e < hi; e += blockDim.x) {
        int cc = col[e];
        int b = cc >> 6;
        int p = lbase[b] + atomicAdd(&cnt2[b], 1);
        int2 v;
        v.x = row[e] | ((cc & 63) << 20);
        v.y = __float_as_int(ew[e]);
        rw[p] = v;
    }
}

// per-bucket: per-node counts -> ptr, dis; node-sorted rw2 (row bits stripped)
__global__ __launch_bounds__(512) void nodesort_kernel(
        const int2* __restrict__ rw, const int* __restrict__ start,
        int2* __restrict__ rw2, int* __restrict__ ptr,
        float* __restrict__ dis, int N, int E, int nbuck) {
    __shared__ int cnt[BS];
    __shared__ float fdeg[BS];
    __shared__ int fill[BS];
    int b = blockIdx.x, tid = threadIdx.x;
    if (tid < BS) { cnt[tid] = 0; fdeg[tid] = 0.f; }
    __syncthreads();
    int s0 = start[b], s1 = start[b + 1];
    for (int e = s0 + tid; e < s1; e += 512) {
        int2 v = rw[e];
        int cl = v.x >> 20;
        atomicAdd(&cnt[cl], 1);
        atomicAdd(&fdeg[cl], __int_as_float(v.y));
    }
    __syncthreads();
    if (tid < BS) {
        int c = cnt[tid];
        int s = c;
        #pragma unroll
        for (int d = 1; d < BS; d <<= 1) {
            int t = __shfl_up(s, d);
            if (tid >= d) s += t;
        }
        int excl = s - c;
        ptr[b * BS + tid] = s0 + excl;
        fill[tid] = excl;
        int node = b * BS + tid;
        if (node < N) dis[node] = rsqrtf(fdeg[tid] + 1.0f);
    }
    __syncthreads();
    for (int e = s0 + tid; e < s1; e += 512) {
        int2 v = rw[e];
        int cl = v.x >> 20;
        int p = s0 + atomicAdd(&fill[cl], 1);
        int2 o;
        o.x = v.x & 0xFFFFF;
        o.y = v.y;
        rw2[p] = o;
    }
    if (b == 0 && tid == 0) ptr[nbuck * BS] = E;
}

// xs1 = (x @ W1^T) * dis   (W1: [32,16] row-major)
__global__ void xw1_kernel(const float* __restrict__ x, const float* __restrict__ W1,
                           const float* __restrict__ dis, float* __restrict__ xs1, int N) {
    __shared__ float sW[512];
    for (int t = threadIdx.x; t < 512; t += blockDim.x) sW[t] = W1[t];
    __syncthreads();
    int i = blockIdx.x * blockDim.x + threadIdx.x;
    if (i >= N) return;
    float d = dis[i];
    float xr[16];
#pragma unroll
    for (int k = 0; k < 4; ++k) {
        float4 v = ((const float4*)(x + (size_t)i * 16))[k];
        xr[4*k+0] = v.x; xr[4*k+1] = v.y; xr[4*k+2] = v.z; xr[4*k+3] = v.w;
    }
    float* outp = xs1 + (size_t)i * 32;
#pragma unroll
    for (int o = 0; o < 32; ++o) {
        float acc = 0.f;
#pragma unroll
        for (int k = 0; k < 16; ++k) acc += xr[k] * sW[o*16 + k];
        outp[o] = acc * d;
    }
}

// wave per node; lane = slot(8) x quad(8); 8 edges per iteration, float4 loads.
// fused: h = relu(dis*(agg+self)+b1); xs2 = (h @ W2^T)*dis  (h via LDS)
__global__ __launch_bounds__(256) void gather1_kernel(
        const int* __restrict__ ptr, const int2* __restrict__ rw2,
        const float* __restrict__ xs1, const float* __restrict__ dis,
        const float* __restrict__ b1, const float* __restrict__ W2,
        float* __restrict__ xs2, int N) {
    __shared__ float sW2[16 * 33];   // padded, conflict-free dot
    __shared__ float hbuf[4 * 32];
    for (int t = threadIdx.x; t < 512; t += 256) sW2[(t >> 5) * 33 + (t & 31)] = W2[t];

    int node = (blockIdx.x * 256 + threadIdx.x) >> 6;
    int wloc = threadIdx.x >> 6;
    int lane = threadIdx.x & 63;
    int slot = lane >> 3;          // 8 edge slots
    int q    = lane & 7;           // 8 float4 quads = 32 features
    bool valid = node < N;

    int s0 = 0, s1 = 0;
    if (valid) { s0 = ptr[node]; s1 = ptr[node + 1]; }

    float4 a0 = {0.f, 0.f, 0.f, 0.f}, a1 = {0.f, 0.f, 0.f, 0.f};
    int e = s0 + slot;
    for (; e + 8 < s1; e += 16) {              // 2-way unroll, stride 8/slot
        int2 v0 = rw2[e];
        int2 v1 = rw2[e + 8];
        float4 x0 = *(const float4*)(xs1 + (size_t)v0.x * 32 + q * 4);
        float4 x1 = *(const float4*)(xs1 + (size_t)v1.x * 32 + q * 4);
        float w0 = __int_as_float(v0.y), w1 = __int_as_float(v1.y);
        a0.x += w0 * x0.x; a0.y += w0 * x0.y; a0.z += w0 * x0.z; a0.w += w0 * x0.w;
        a1.x += w1 * x1.x; a1.y += w1 * x1.y; a1.z += w1 * x1.z; a1.w += w1 * x1.w;
    }
    if (e < s1) {
        int2 v0 = rw2[e];
        float4 x0 = *(const float4*)(xs1 + (size_t)v0.x * 32 + q * 4);
        float w0 = __int_as_float(v0.y);
        a0.x += w0 * x0.x; a0.y += w0 * x0.y; a0.z += w0 * x0.z; a0.w += w0 * x0.w;
    }
    a0.x += a1.x; a0.y += a1.y; a0.z += a1.z; a0.w += a1.w;
#pragma unroll
    for (int m = 8; m <= 32; m <<= 1) {        // reduce across 8 slots
        a0.x += __shfl_xor(a0.x, m);
        a0.y += __shfl_xor(a0.y, m);
        a0.z += __shfl_xor(a0.z, m);
        a0.w += __shfl_xor(a0.w, m);
    }

    float d = valid ? dis[node] : 0.f;
    if (valid && slot == 0) {
        float4 self = *(const float4*)(xs1 + (size_t)node * 32 + q * 4);
        float4 bb   = *(const float4*)(b1 + q * 4);
        float4 h;
        h.x = fmaxf(d * (a0.x + self.x) + bb.x, 0.f);
        h.y = fmaxf(d * (a0.y + self.y) + bb.y, 0.f);
        h.z = fmaxf(d * (a0.z + self.z) + bb.z, 0.f);
        h.w = fmaxf(d * (a0.w + self.w) + bb.w, 0.f);
        *(float4*)(hbuf + wloc * 32 + q * 4) = h;
    }
    __syncthreads();

    if (valid && lane < 16) {
        float a = 0.f;
#pragma unroll
        for (int k = 0; k < 32; ++k) a += hbuf[wloc * 32 + k] * sW2[lane * 33 + k];
        xs2[(size_t)node * 16 + lane] = a * d;
    }
}

// wave per node; lane = slot(16) x quad(4); 16 edges per iteration.
__global__ __launch_bounds__(256) void gather2_kernel(
        const int* __restrict__ ptr, const int2* __restrict__ rw2,
        const float* __restrict__ xs2, const float* __restrict__ dis,
        const float* __restrict__ b2, float* __restrict__ out, int N) {
    int node = (blockIdx.x * 256 + threadIdx.x) >> 6;
    int lane = threadIdx.x & 63;
    int slot = lane >> 2;          // 16 edge slots
    int q    = lane & 3;           // 4 float4 quads = 16 features
    if (node >= N) return;
    int s0 = ptr[node], s1 = ptr[node + 1];

    float4 a0 = {0.f, 0.f, 0.f, 0.f}, a1 = {0.f, 0.f, 0.f, 0.f};
    int e = s0 + slot;
    for (; e + 16 < s1; e += 32) {             // 2-way unroll, stride 16/slot
        int2 v0 = rw2[e];
        int2 v1 = rw2[e + 16];
        float4 x0 = *(const float4*)(xs2 + (size_t)v0.x * 16 + q * 4);
        float4 x1 = *(const float4*)(xs2 + (size_t)v1.x * 16 + q * 4);
        float w0 = __int_as_float(v0.y), w1 = __int_as_float(v1.y);
        a0.x += w0 * x0.x; a0.y += w0 * x0.y; a0.z += w0 * x0.z; a0.w += w0 * x0.w;
        a1.x += w1 * x1.x; a1.y += w1 * x1.y; a1.z += w1 * x1.z; a1.w += w1 * x1.w;
    }
    if (e < s1) {
        int2 v0 = rw2[e];
        float4 x0 = *(const float4*)(xs2 + (size_t)v0.x * 16 + q * 4);
        float w0 = __int_as_float(v0.y);
        a0.x += w0 * x0.x; a0.y += w0 * x0.y; a0.z += w0 * x0.z; a0.w += w0 * x0.w;
    }
    a0.x += a1.x; a0.y += a1.y; a0.z += a1.z; a0.w += a1.w;
#pragma unroll
    for (int m = 4; m <= 32; m <<= 1) {        // reduce across 16 slots
        a0.x += __shfl_xor(a0.x, m);
        a0.y += __shfl_xor(a0.y, m);
        a0.z += __shfl_xor(a0.z, m);
        a0.w += __shfl_xor(a0.w, m);
    }

    if (slot == 0) {
        float d = dis[node];
        float4 self = *(const float4*)(xs2 + (size_t)node * 16 + q * 4);
        float4 bb   = *(const float4*)(b2 + q * 4);
        float4 o;
        o.x = d * (a0.x + self.x) + bb.x;
        o.y = d * (a0.y + self.y) + bb.y;
        o.z = d * (a0.z + self.z) + bb.z;
        o.w = d * (a0.w + self.w) + bb.w;
        *(float4*)(out + (size_t)node * 16 + q * 4) = o;
    }
}

extern "C" void kernel_launch(void* const* d_in, const int* in_sizes, int n_in,
                              void* d_out, int out_size, void* d_ws, size_t ws_size,
                              hipStream_t stream) {
    const float* x  = (const float*)d_in[0];
    const int*   ei = (const int*)d_in[1];   // [2, E] int32
    const float* ew = (const float*)d_in[2];
    const float* W1 = (const float*)d_in[3];
    const float* b1 = (const float*)d_in[4];
    const float* W2 = (const float*)d_in[5];
    const float* b2 = (const float*)d_in[6];
    float* out = (float*)d_out;

    const int N = in_sizes[0] / 16;
    const int E = in_sizes[2];
    const int* row = ei;
    const int* col = ei + E;

    const int nbuck = (N + BS - 1) / BS;          // 1563
    const int per   = (E + CHUNKS - 1) / CHUNKS;
    const int nb    = (nbuck + 255) / 256;        // 7

    // workspace layout (4B units)
    //  [0, 2E)   : rw2 (node-sorted int2)
    //  [2E, 4E)  : rw (bucket-sorted int2), DEAD after nodesort;
    //              reused: xs1 [32N] at 2E, xs2 [16N] at 2E+32N (48N <= 2E)
    //  [4E, ...) : dis[N], ptr[BS*nbuck+1], part, base, tot, start, bsum
    float* ws    = (float*)d_ws;
    int2*  rw2   = (int2*)ws;
    int2*  rw    = (int2*)(ws + (size_t)2 * E);
    float* xs1   = ws + (size_t)2 * E;
    float* xs2   = xs1 + (size_t)N * 32;
    float* dis   = ws + (size_t)4 * E;
    int*   ptr   = (int*)(dis + N);
    int*   part  = ptr + (size_t)BS * nbuck + 1;
    int*   base  = part + (size_t)CHUNKS * nbuck;
    int*   tot   = base + (size_t)CHUNKS * nbuck;
    int*   start = tot + nbuck;
    int*   bsum  = start + nbuck + 1;

    hist_kernel<<<CHUNKS, 1024, nbuck * 4, stream>>>(col, part, E, nbuck, per);
    colscan_kernel<<<nbuck, 64, 0, stream>>>(part, base, tot, nbuck);
    scan1_kernel<<<nb, 256, 0, stream>>>(tot, start, bsum, nbuck);
    scan2_kernel<<<1, 512, 0, stream>>>(bsum, nb);
    scan3_kernel<<<(nbuck + 256) / 256 + 1, 256, 0, stream>>>(start, bsum, nbuck, E);
    place_kernel<<<CHUNKS, 1024, 2 * nbuck * 4, stream>>>(row, col, ew, start, base, rw, E, nbuck, per);
    nodesort_kernel<<<nbuck, 512, 0, stream>>>(rw, start, rw2, ptr, dis, N, E, nbuck);

    xw1_kernel<<<(N + 255) / 256, 256, 0, stream>>>(x, W1, dis, xs1, N);
    gather1_kernel<<<(N + 3) / 4, 256, 0, stream>>>(ptr, rw2, xs1, dis, b1, W2, xs2, N);
    gather2_kernel<<<(N + 3) / 4, 256, 0, stream>>>(ptr, rw2, xs2, dis, b2, out, N);
}

// Round 7
// 209.402 us; speedup vs baseline: 5.0336x; 1.0361x over previous
//
#include <hip/hip_runtime.h>
#include <cstdint>

// ---------------------------------------------------------------------------
// 2-layer GCN, zero scattered global atomics, per-node CSR gather.
// Layer 1 aggregates PRE-transform (AX then @W1^T) so both gathers are
// 64 B/edge; W1+relu+W2 run fused in gather1's epilogue via LDS.
//
//  K1 hist:     per-chunk LDS histogram of bucket=col>>6 -> part[C][NB]
//  K2 colscan:  per-bucket scan over chunks -> base[C][NB], tot[NB]
//  scan1/2/3:   exclusive scan tot -> start[NB+1]
//  K4 place:    rw[pos] = {row | cl<<20, ew}  (bucket-sorted, normal stores)
//  K5 nodesort: per-bucket LDS count/scan -> ptr[node], dis=rsqrt(deg+1),
//               rw2 = node-sorted edge list {row, ew}
//  K6 xsc:      xsc = x * dis                                   [N,16]
//  K7 gather1:  wave/node: t = dis*(sum w*xsc[r] + xsc_self);
//               h = relu(t@W1^T + b1); xs2 = (h@W2^T)*dis  (all in LDS)
//  K8 gather2:  wave/node: out = dis*(sum w*xs2[r] + xs2_self)+b2
// ---------------------------------------------------------------------------

#define BS 64
#define CHUNKS 512

__global__ __launch_bounds__(1024) void hist_kernel(
        const int* __restrict__ col, int* __restrict__ part,
        int E, int nbuck, int per) {
    extern __shared__ int sh[];
    for (int t = threadIdx.x; t < nbuck; t += blockDim.x) sh[t] = 0;
    __syncthreads();
    int lo = blockIdx.x * per, hi = min(E, lo + per);
    for (int e = lo + threadIdx.x; e < hi; e += blockDim.x)
        atomicAdd(&sh[col[e] >> 6], 1);
    __syncthreads();
    for (int t = threadIdx.x; t < nbuck; t += blockDim.x)
        part[(size_t)blockIdx.x * nbuck + t] = sh[t];
}

__global__ void colscan_kernel(const int* __restrict__ part, int* __restrict__ base,
                               int* __restrict__ tot, int nbuck) {
    int b = blockIdx.x;
    if (b >= nbuck) return;
    int lane = threadIdx.x;  // 64
    int off = 0;
    for (int g = 0; g < CHUNKS; g += 64) {
        int c = g + lane;
        int v = part[(size_t)c * nbuck + b];
        int s = v;
        #pragma unroll
        for (int d = 1; d < 64; d <<= 1) {
            int t = __shfl_up(s, d);
            if (lane >= d) s += t;
        }
        base[(size_t)c * nbuck + b] = off + (s - v);
        off += __shfl(s, 63);
    }
    if (lane == 0) tot[b] = off;
}

__global__ void scan1_kernel(const int* __restrict__ cnt, int* __restrict__ excl,
                             int* __restrict__ bsum, int n) {
    __shared__ int s[256];
    int tid = threadIdx.x;
    int i = blockIdx.x * 256 + tid;
    int v = (i < n) ? cnt[i] : 0;
    s[tid] = v;
    __syncthreads();
    for (int off = 1; off < 256; off <<= 1) {
        int t = (tid >= off) ? s[tid - off] : 0;
        __syncthreads();
        s[tid] += t;
        __syncthreads();
    }
    if (i < n) excl[i] = s[tid] - v;
    if (tid == 255) bsum[blockIdx.x] = s[255];
}

__global__ void scan2_kernel(int* __restrict__ bsum, int nb) {
    __shared__ int s[512];
    int tid = threadIdx.x;
    int v = (tid < nb) ? bsum[tid] : 0;
    s[tid] = v;
    __syncthreads();
    for (int off = 1; off < 512; off <<= 1) {
        int t = (tid >= off) ? s[tid - off] : 0;
        __syncthreads();
        s[tid] += t;
        __syncthreads();
    }
    if (tid < nb) bsum[tid] = s[tid] - v;
}

__global__ void scan3_kernel(int* __restrict__ excl, const int* __restrict__ bsum,
                             int n, int E) {
    int i = blockIdx.x * 256 + threadIdx.x;
    if (i < n) excl[i] += bsum[i >> 8];
    else if (i == n) excl[n] = E;
}

__global__ __launch_bounds__(1024) void place_kernel(
        const int* __restrict__ row, const int* __restrict__ col,
        const float* __restrict__ ew,
        const int* __restrict__ start, const int* __restrict__ base,
        int2* __restrict__ rw, int E, int nbuck, int per) {
    extern __shared__ int sh[];
    int* lbase = sh;
    int* cnt2  = sh + nbuck;
    int c = blockIdx.x;
    for (int t = threadIdx.x; t < nbuck; t += blockDim.x) {
        lbase[t] = start[t] + base[(size_t)c * nbuck + t];
        cnt2[t] = 0;
    }
    __syncthreads();
    int lo = c * per, hi = min(E, lo + per);
    for (int e = lo + threadIdx.x; e < hi; e += blockDim.x) {
        int cc = col[e];
        int b = cc >> 6;
        int p = lbase[b] + atomicAdd(&cnt2[b], 1);
        int2 v;
        v.x = row[e] | ((cc & 63) << 20);
        v.y = __float_as_int(ew[e]);
        rw[p] = v;
    }
}

// per-bucket: per-node counts -> ptr, dis; node-sorted rw2 (row bits stripped)
__global__ __launch_bounds__(512) void nodesort_kernel(
        const int2* __restrict__ rw, const int* __restrict__ start,
        int2* __restrict__ rw2, int* __restrict__ ptr,
        float* __restrict__ dis, int N, int E, int nbuck) {
    __shared__ int cnt[BS];
    __shared__ float fdeg[BS];
    __shared__ int fill[BS];
    int b = blockIdx.x, tid = threadIdx.x;
    if (tid < BS) { cnt[tid] = 0; fdeg[tid] = 0.f; }
    __syncthreads();
    int s0 = start[b], s1 = start[b + 1];
    for (int e = s0 + tid; e < s1; e += 512) {
        int2 v = rw[e];
        int cl = v.x >> 20;
        atomicAdd(&cnt[cl], 1);
        atomicAdd(&fdeg[cl], __int_as_float(v.y));
    }
    __syncthreads();
    if (tid < BS) {
        int c = cnt[tid];
        int s = c;
        #pragma unroll
        for (int d = 1; d < BS; d <<= 1) {
            int t = __shfl_up(s, d);
            if (tid >= d) s += t;
        }
        int excl = s - c;
        ptr[b * BS + tid] = s0 + excl;
        fill[tid] = excl;
        int node = b * BS + tid;
        if (node < N) dis[node] = rsqrtf(fdeg[tid] + 1.0f);
    }
    __syncthreads();
    for (int e = s0 + tid; e < s1; e += 512) {
        int2 v = rw[e];
        int cl = v.x >> 20;
        int p = s0 + atomicAdd(&fill[cl], 1);
        int2 o;
        o.x = v.x & 0xFFFFF;
        o.y = v.y;
        rw2[p] = o;
    }
    if (b == 0 && tid == 0) ptr[nbuck * BS] = E;
}

// xsc = x * dis   (one float4 per thread)
__global__ void xsc_kernel(const float* __restrict__ x, const float* __restrict__ dis,
                           float* __restrict__ xsc, int N) {
    int gid = blockIdx.x * 256 + threadIdx.x;
    if (gid >= N * 4) return;
    int node = gid >> 2;
    float d = dis[node];
    float4 v = ((const float4*)x)[gid];
    v.x *= d; v.y *= d; v.z *= d; v.w *= d;
    ((float4*)xsc)[gid] = v;
}

// wave per node; lane = slot(16) x quad(4); 16 edges/iter, 64 B gathers.
// epilogue (LDS): t = dis*(agg+self); h = relu(t@W1^T+b1); xs2 = (h@W2^T)*dis
__global__ __launch_bounds__(256) void gather1_kernel(
        const int* __restrict__ ptr, const int2* __restrict__ rw2,
        const float* __restrict__ xsc, const float* __restrict__ dis,
        const float* __restrict__ b1, const float* __restrict__ W1,
        const float* __restrict__ W2, float* __restrict__ xs2, int N) {
    __shared__ float sW1[32 * 17];   // W1 [32][16] padded
    __shared__ float sW2[16 * 33];   // W2 [16][32] padded
    __shared__ float sb1[32];
    __shared__ float tbuf[4 * 16];
    __shared__ float hbuf[4 * 32];
    for (int t = threadIdx.x; t < 512; t += 256) {
        sW1[(t >> 4) * 17 + (t & 15)] = W1[t];
        sW2[(t >> 5) * 33 + (t & 31)] = W2[t];
    }
    if (threadIdx.x < 32) sb1[threadIdx.x] = b1[threadIdx.x];

    int node = (blockIdx.x * 256 + threadIdx.x) >> 6;
    int wloc = threadIdx.x >> 6;
    int lane = threadIdx.x & 63;
    int slot = lane >> 2;          // 16 edge slots
    int q    = lane & 3;           // 4 float4 quads = 16 features
    bool valid = node < N;

    int s0 = 0, s1 = 0;
    if (valid) { s0 = ptr[node]; s1 = ptr[node + 1]; }

    float4 a0 = {0.f, 0.f, 0.f, 0.f}, a1 = {0.f, 0.f, 0.f, 0.f};
    int e = s0 + slot;
    for (; e + 16 < s1; e += 32) {             // 2-way unroll, stride 16/slot
        int2 v0 = rw2[e];
        int2 v1 = rw2[e + 16];
        float4 x0 = *(const float4*)(xsc + (size_t)v0.x * 16 + q * 4);
        float4 x1 = *(const float4*)(xsc + (size_t)v1.x * 16 + q * 4);
        float w0 = __int_as_float(v0.y), w1 = __int_as_float(v1.y);
        a0.x += w0 * x0.x; a0.y += w0 * x0.y; a0.z += w0 * x0.z; a0.w += w0 * x0.w;
        a1.x += w1 * x1.x; a1.y += w1 * x1.y; a1.z += w1 * x1.z; a1.w += w1 * x1.w;
    }
    if (e < s1) {
        int2 v0 = rw2[e];
        float4 x0 = *(const float4*)(xsc + (size_t)v0.x * 16 + q * 4);
        float w0 = __int_as_float(v0.y);
        a0.x += w0 * x0.x; a0.y += w0 * x0.y; a0.z += w0 * x0.z; a0.w += w0 * x0.w;
    }
    a0.x += a1.x; a0.y += a1.y; a0.z += a1.z; a0.w += a1.w;
#pragma unroll
    for (int m = 4; m <= 32; m <<= 1) {        // reduce across 16 slots
        a0.x += __shfl_xor(a0.x, m);
        a0.y += __shfl_xor(a0.y, m);
        a0.z += __shfl_xor(a0.z, m);
        a0.w += __shfl_xor(a0.w, m);
    }

    float d = valid ? dis[node] : 0.f;
    if (valid && slot == 0) {
        float4 self = *(const float4*)(xsc + (size_t)node * 16 + q * 4);
        float4 t4;
        t4.x = d * (a0.x + self.x);
        t4.y = d * (a0.y + self.y);
        t4.z = d * (a0.z + self.z);
        t4.w = d * (a0.w + self.w);
        *(float4*)(tbuf + wloc * 16 + q * 4) = t4;
    }
    __syncthreads();

    if (valid && lane < 32) {                  // h = relu(t @ W1^T + b1)
        float acc = sb1[lane];
#pragma unroll
        for (int k = 0; k < 16; ++k) acc += tbuf[wloc * 16 + k] * sW1[lane * 17 + k];
        hbuf[wloc * 32 + lane] = fmaxf(acc, 0.f);
    }
    __syncthreads();

    if (valid && lane < 16) {                  // xs2 = (h @ W2^T) * dis
        float acc = 0.f;
#pragma unroll
        for (int k = 0; k < 32; ++k) acc += hbuf[wloc * 32 + k] * sW2[lane * 33 + k];
        xs2[(size_t)node * 16 + lane] = acc * d;
    }
}

// wave per node; lane = slot(16) x quad(4); 16 edges per iteration.
__global__ __launch_bounds__(256) void gather2_kernel(
        const int* __restrict__ ptr, const int2* __restrict__ rw2,
        const float* __restrict__ xs2, const float* __restrict__ dis,
        const float* __restrict__ b2, float* __restrict__ out, int N) {
    int node = (blockIdx.x * 256 + threadIdx.x) >> 6;
    int lane = threadIdx.x & 63;
    int slot = lane >> 2;          // 16 edge slots
    int q    = lane & 3;           // 4 float4 quads = 16 features
    if (node >= N) return;
    int s0 = ptr[node], s1 = ptr[node + 1];

    float4 a0 = {0.f, 0.f, 0.f, 0.f}, a1 = {0.f, 0.f, 0.f, 0.f};
    int e = s0 + slot;
    for (; e + 16 < s1; e += 32) {             // 2-way unroll, stride 16/slot
        int2 v0 = rw2[e];
        int2 v1 = rw2[e + 16];
        float4 x0 = *(const float4*)(xs2 + (size_t)v0.x * 16 + q * 4);
        float4 x1 = *(const float4*)(xs2 + (size_t)v1.x * 16 + q * 4);
        float w0 = __int_as_float(v0.y), w1 = __int_as_float(v1.y);
        a0.x += w0 * x0.x; a0.y += w0 * x0.y; a0.z += w0 * x0.z; a0.w += w0 * x0.w;
        a1.x += w1 * x1.x; a1.y += w1 * x1.y; a1.z += w1 * x1.z; a1.w += w1 * x1.w;
    }
    if (e < s1) {
        int2 v0 = rw2[e];
        float4 x0 = *(const float4*)(xs2 + (size_t)v0.x * 16 + q * 4);
        float w0 = __int_as_float(v0.y);
        a0.x += w0 * x0.x; a0.y += w0 * x0.y; a0.z += w0 * x0.z; a0.w += w0 * x0.w;
    }
    a0.x += a1.x; a0.y += a1.y; a0.z += a1.z; a0.w += a1.w;
#pragma unroll
    for (int m = 4; m <= 32; m <<= 1) {        // reduce across 16 slots
        a0.x += __shfl_xor(a0.x, m);
        a0.y += __shfl_xor(a0.y, m);
        a0.z += __shfl_xor(a0.z, m);
        a0.w += __shfl_xor(a0.w, m);
    }

    if (slot == 0) {
        float d = dis[node];
        float4 self = *(const float4*)(xs2 + (size_t)node * 16 + q * 4);
        float4 bb   = *(const float4*)(b2 + q * 4);
        float4 o;
        o.x = d * (a0.x + self.x) + bb.x;
        o.y = d * (a0.y + self.y) + bb.y;
        o.z = d * (a0.z + self.z) + bb.z;
        o.w = d * (a0.w + self.w) + bb.w;
        *(float4*)(out + (size_t)node * 16 + q * 4) = o;
    }
}

extern "C" void kernel_launch(void* const* d_in, const int* in_sizes, int n_in,
                              void* d_out, int out_size, void* d_ws, size_t ws_size,
                              hipStream_t stream) {
    const float* x  = (const float*)d_in[0];
    const int*   ei = (const int*)d_in[1];   // [2, E] int32
    const float* ew = (const float*)d_in[2];
    const float* W1 = (const float*)d_in[3];
    const float* b1 = (const float*)d_in[4];
    const float* W2 = (const float*)d_in[5];
    const float* b2 = (const float*)d_in[6];
    float* out = (float*)d_out;

    const int N = in_sizes[0] / 16;
    const int E = in_sizes[2];
    const int* row = ei;
    const int* col = ei + E;

    const int nbuck = (N + BS - 1) / BS;          // 1563
    const int per   = (E + CHUNKS - 1) / CHUNKS;
    const int nb    = (nbuck + 255) / 256;        // 7

    // workspace layout (4B units)
    //  [0, 2E)   : rw2 (node-sorted int2)
    //  [2E, 4E)  : rw (bucket-sorted int2), DEAD after nodesort;
    //              reused: xsc [16N] at 2E, xs2 [16N] at 2E+16N (32N <= 2E)
    //  [4E, ...) : dis[N], ptr[BS*nbuck+1], part, base, tot, start, bsum
    float* ws    = (float*)d_ws;
    int2*  rw2   = (int2*)ws;
    int2*  rw    = (int2*)(ws + (size_t)2 * E);
    float* xsc   = ws + (size_t)2 * E;
    float* xs2   = xsc + (size_t)N * 16;
    float* dis   = ws + (size_t)4 * E;
    int*   ptr   = (int*)(dis + N);
    int*   part  = ptr + (size_t)BS * nbuck + 1;
    int*   base  = part + (size_t)CHUNKS * nbuck;
    int*   tot   = base + (size_t)CHUNKS * nbuck;
    int*   start = tot + nbuck;
    int*   bsum  = start + nbuck + 1;

    hist_kernel<<<CHUNKS, 1024, nbuck * 4, stream>>>(col, part, E, nbuck, per);
    colscan_kernel<<<nbuck, 64, 0, stream>>>(part, base, tot, nbuck);
    scan1_kernel<<<nb, 256, 0, stream>>>(tot, start, bsum, nbuck);
    scan2_kernel<<<1, 512, 0, stream>>>(bsum, nb);
    scan3_kernel<<<(nbuck + 256) / 256 + 1, 256, 0, stream>>>(start, bsum, nbuck, E);
    place_kernel<<<CHUNKS, 1024, 2 * nbuck * 4, stream>>>(row, col, ew, start, base, rw, E, nbuck, per);
    nodesort_kernel<<<nbuck, 512, 0, stream>>>(rw, start, rw2, ptr, dis, N, E, nbuck);

    xsc_kernel<<<(N * 4 + 255) / 256, 256, 0, stream>>>(x, dis, xsc, N);
    gather1_kernel<<<(N + 3) / 4, 256, 0, stream>>>(ptr, rw2, xsc, dis, b1, W1, W2, xs2, N);
    gather2_kernel<<<(N + 3) / 4, 256, 0, stream>>>(ptr, rw2, xs2, dis, b2, out, N);
}